// Round 2
// baseline (130.717 us; speedup 1.0000x reference)
//
#include <hip/hip_runtime.h>
#include <hip/hip_bf16.h>
#include <math.h>
#include <float.h>

#define BB 256
#define NN 400
#define DD 512
#define KK 20

// ---------------- Kernel A: scorer = tanh(h_t @ W^T + b), plus inv_norm ----------------
__global__ __launch_bounds__(256) void scorer_kernel(
    const float* __restrict__ h_t,      // [B, D]
    const float* __restrict__ W,        // [D, D] row-major; scorer[d] = sum_j h[j]*W[d,j]
    const float* __restrict__ bmap,     // [D]
    float* __restrict__ scorer_ws,      // [B, D] f32
    float* __restrict__ inv_norm,       // [B]
    float* __restrict__ scorer_out)     // [B, D] f32 (output 2)
{
    const int b = blockIdx.x;
    const int t = threadIdx.x;
    const int wave = t >> 6, lane = t & 63;

    __shared__ float h[DD];
    __shared__ float sc[DD];
    __shared__ float red[4];

    h[t]       = h_t[b * DD + t];
    h[t + 256] = h_t[b * DD + 256 + t];
    __syncthreads();

    // hoist h fragment for this lane (same for every output row)
    const float4 h0 = ((const float4*)h)[lane];
    const float4 h1 = ((const float4*)h)[lane + 64];

    for (int d = wave; d < DD; d += 4) {
        const float4* wp = (const float4*)(W + (size_t)d * DD);
        float4 a0 = wp[lane];
        float4 a1 = wp[lane + 64];
        float s = a0.x * h0.x + a0.y * h0.y + a0.z * h0.z + a0.w * h0.w
                + a1.x * h1.x + a1.y * h1.y + a1.z * h1.z + a1.w * h1.w;
        #pragma unroll
        for (int off = 32; off; off >>= 1) s += __shfl_xor(s, off, 64);
        if (lane == 0) sc[d] = tanhf(s + bmap[d]);
    }
    __syncthreads();

    const float v0 = sc[t];
    const float v1 = sc[t + 256];
    float ss = v0 * v0 + v1 * v1;
    #pragma unroll
    for (int off = 32; off; off >>= 1) ss += __shfl_xor(ss, off, 64);
    if (lane == 0) red[wave] = ss;
    __syncthreads();
    if (t == 0) {
        float tot = red[0] + red[1] + red[2] + red[3];
        inv_norm[b] = 1.0f / sqrtf(tot);
    }
    scorer_ws[b * DD + t]        = v0;
    scorer_ws[b * DD + 256 + t]  = v1;
    scorer_out[b * DD + t]       = v0;
    scorer_out[b * DD + 256 + t] = v1;
}

// ---------------- Kernel B: scores[b,n] = dot(node_embs[b,n,:], scorer[b,:]) * inv_norm[b] ----------------
// grid = B * 25 blocks; block = 256 (4 waves); each wave computes 4 rows.
__global__ __launch_bounds__(256) void scores_kernel(
    const float* __restrict__ embs,     // [B, N, D]
    const float* __restrict__ scorer_ws,// [B, D]
    const float* __restrict__ inv_norm, // [B]
    float* __restrict__ scores)         // [B, N]
{
    const int blk = blockIdx.x;
    const int b = blk / 25;
    const int chunk = blk % 25;
    const int t = threadIdx.x;
    const int wave = t >> 6, lane = t & 63;

    __shared__ float sh[DD];
    sh[t]       = scorer_ws[b * DD + t];
    sh[t + 256] = scorer_ws[b * DD + 256 + t];
    __syncthreads();

    const float inv = inv_norm[b];
    const float4 h0 = ((const float4*)sh)[lane];
    const float4 h1 = ((const float4*)sh)[lane + 64];

    const int n0 = chunk * 16 + wave * 4;
    const float* base = embs + ((size_t)b * NN + n0) * DD;

    #pragma unroll
    for (int r = 0; r < 4; ++r) {
        const float4* p = (const float4*)(base + (size_t)r * DD);
        float4 a0 = p[lane];
        float4 a1 = p[lane + 64];
        float s = a0.x * h0.x + a0.y * h0.y + a0.z * h0.z + a0.w * h0.w
                + a1.x * h1.x + a1.y * h1.y + a1.z * h1.z + a1.w * h1.w;
        #pragma unroll
        for (int off = 32; off; off >>= 1) s += __shfl_xor(s, off, 64);
        if (lane == 0) scores[b * NN + n0 + r] = s * inv;
    }
}

// ---------------- Kernel C: per-batch topk, softmax stats, gather, outputs ----------------
__global__ __launch_bounds__(256) void finalize_kernel(
    const float* __restrict__ embs,     // [B, N, D]
    const float* __restrict__ scores,   // [B, N]
    float* __restrict__ out0,           // [B, K, K] (transposed: out0[b,j,k])
    float* __restrict__ out1,           // [B] policy_score
    float* __restrict__ out3,           // [B] entropy
    float* __restrict__ out4)           // [B, K] indices (as float)
{
    const int b = blockIdx.x;
    const int t = threadIdx.x;
    const int wave = t >> 6, lane = t & 63;

    __shared__ float s[NN];
    __shared__ float work[NN];
    __shared__ float redf[4];
    __shared__ float redf2[4];
    __shared__ int   redi[4];
    __shared__ int   topk[KK];
    __shared__ float lp[KK];
    __shared__ float th[KK];
    __shared__ float mZ[3]; // m, Z, Wsum

    for (int i = t; i < NN; i += 256) {
        float v = scores[b * NN + i];
        s[i] = v;
        work[i] = v;
    }
    __syncthreads();

    // --- block max ---
    float m = -FLT_MAX;
    for (int i = t; i < NN; i += 256) m = fmaxf(m, s[i]);
    #pragma unroll
    for (int off = 32; off; off >>= 1) m = fmaxf(m, __shfl_xor(m, off, 64));
    if (lane == 0) redf[wave] = m;
    __syncthreads();
    if (t == 0) mZ[0] = fmaxf(fmaxf(redf[0], redf[1]), fmaxf(redf[2], redf[3]));
    __syncthreads();
    m = mZ[0];

    // --- Z = sum exp(x), Wsum = sum exp(x)*x ---
    float z = 0.f, w = 0.f;
    for (int i = t; i < NN; i += 256) {
        float x = s[i] - m;
        float e = expf(x);
        z += e;
        w += e * x;
    }
    #pragma unroll
    for (int off = 32; off; off >>= 1) {
        z += __shfl_xor(z, off, 64);
        w += __shfl_xor(w, off, 64);
    }
    if (lane == 0) { redf[wave] = z; redf2[wave] = w; }
    __syncthreads();
    if (t == 0) {
        mZ[1] = redf[0] + redf[1] + redf[2] + redf[3];
        mZ[2] = redf2[0] + redf2[1] + redf2[2] + redf2[3];
    }
    __syncthreads();
    const float Z = mZ[1];
    const float Wsum = mZ[2];
    const float logZ = logf(Z);

    if (t == 0) out3[b] = logZ - Wsum / Z; // entropy

    // --- top-K: iterative block argmax with smaller-index tie-break ---
    for (int k = 0; k < KK; ++k) {
        float v = -FLT_MAX;
        int id = 0x7fffffff;
        if (t < NN) { v = work[t]; id = t; }
        if (t + 256 < NN) {
            float v2 = work[t + 256];
            if (v2 > v) { v = v2; id = t + 256; }
        }
        #pragma unroll
        for (int off = 32; off; off >>= 1) {
            float ov = __shfl_xor(v, off, 64);
            int oid = __shfl_xor(id, off, 64);
            if (ov > v || (ov == v && oid < id)) { v = ov; id = oid; }
        }
        if (lane == 0) { redf[wave] = v; redi[wave] = id; }
        __syncthreads();
        if (t == 0) {
            float bv = redf[0]; int bi = redi[0];
            #pragma unroll
            for (int ww = 1; ww < 4; ++ww) {
                if (redf[ww] > bv || (redf[ww] == bv && redi[ww] < bi)) { bv = redf[ww]; bi = redi[ww]; }
            }
            topk[k] = bi;
            work[bi] = -FLT_MAX;
        }
        __syncthreads();
    }

    // --- per-k values ---
    if (t < KK) {
        int idx = topk[t];
        float sk = s[idx];
        lp[t] = (sk - m) - logZ;
        th[t] = tanhf(sk);
        out4[b * KK + t] = (float)idx;
    }
    __syncthreads();
    if (t == 0) {
        float acc = 0.f;
        #pragma unroll
        for (int k = 0; k < KK; ++k) acc += lp[k];
        out1[b] = acc / (float)KK;
    }

    // --- out0[b, j, k] = embs[b, topk[k], j] * tanh_s[k], j,k < 20 ---
    if (t < NN) { // 400 = 20*20 elements
        int j = t / KK;
        int k = t - j * KK;
        float val = embs[((size_t)b * NN + topk[k]) * DD + j] * th[k];
        out0[(size_t)b * (KK * KK) + t] = val;
    }
}

extern "C" void kernel_launch(void* const* d_in, const int* in_sizes, int n_in,
                              void* d_out, int out_size, void* d_ws, size_t ws_size,
                              hipStream_t stream) {
    const float* node_embs = (const float*)d_in[0];
    // d_in[1] = mask, unused
    const float* h_t   = (const float*)d_in[2];
    const float* W_map = (const float*)d_in[3];
    const float* b_map = (const float*)d_in[4];

    float* ob = (float*)d_out;
    float* out0 = ob;                       // [B,K,K] -> 102400
    float* out1 = ob + 102400;              // [B]     -> 256
    float* out2 = ob + 102656;              // [B,D]   -> 131072
    float* out3 = ob + 233728;              // [B]     -> 256
    float* out4 = ob + 233984;              // [B,K]   -> 5120

    float* ws_f = (float*)d_ws;
    float* scorer_ws = ws_f;                 // B*D = 131072
    float* inv_norm  = ws_f + 131072;        // B   = 256
    float* scores    = ws_f + 131328;        // B*N = 102400

    scorer_kernel<<<BB, 256, 0, stream>>>(h_t, W_map, b_map, scorer_ws, inv_norm, out2);
    scores_kernel<<<BB * 25, 256, 0, stream>>>(node_embs, scorer_ws, inv_norm, scores);
    finalize_kernel<<<BB, 256, 0, stream>>>(node_embs, scores, out0, out1, out3, out4);
}

// Round 3
// 66.347 us; speedup vs baseline: 1.9702x; 1.9702x over previous
//
#include <hip/hip_runtime.h>
#include <math.h>
#include <float.h>

#define BB 256
#define NN 400
#define DD 512
#define KK 20

__device__ __forceinline__ float dot8(float4 a0, float4 a1, float4 b0, float4 b1) {
    return a0.x*b0.x + a0.y*b0.y + a0.z*b0.z + a0.w*b0.w
         + a1.x*b1.x + a1.y*b1.y + a1.z*b1.z + a1.w*b1.w;
}

// One block per batch. 1024 threads = 16 waves (4/SIMD for latency hiding).
__global__ __launch_bounds__(1024, 4) void fused_topk_kernel(
    const float* __restrict__ embs,   // [B, N, D]
    const float* __restrict__ h_t,    // [B, D]
    const float* __restrict__ W,      // [D, D]
    const float* __restrict__ bmap,   // [D]
    float* __restrict__ out0,         // [B, K, K]
    float* __restrict__ out1,         // [B]
    float* __restrict__ out2,         // [B, D] scorer
    float* __restrict__ out3,         // [B] entropy
    float* __restrict__ out4)         // [B, K] indices as float
{
    const int b = blockIdx.x;
    const int t = threadIdx.x;
    const int wave = t >> 6, lane = t & 63;

    __shared__ float sh_sc[DD];
    __shared__ float sh_s[NN];
    __shared__ float redf[16], redf2[16], redq[8];
    __shared__ float mZ[3];          // inv_norm, m, logZ
    __shared__ int   sh_topk[KK];
    __shared__ float sh_th[KK];

    // h fragment straight from global (same 2KB for all 16 waves; L1-resident)
    const float4* hp = (const float4*)(h_t + (size_t)b * DD);
    const float4 h0 = hp[lane];
    const float4 h1 = hp[lane + 64];

    // ---- Phase A: scorer rows [32w, 32w+32), 16 pairs per wave ----
    {
        const int d0 = wave * 32;
        #pragma unroll 4
        for (int p = 0; p < 16; ++p) {
            const int d = d0 + p * 2;
            const float4* wp0 = (const float4*)(W + (size_t)d * DD);
            const float4* wp1 = (const float4*)(W + (size_t)(d + 1) * DD);
            float4 a0 = wp0[lane], a1 = wp0[lane + 64];
            float4 c0 = wp1[lane], c1 = wp1[lane + 64];
            float s0 = dot8(a0, a1, h0, h1);
            float s1 = dot8(c0, c1, h0, h1);
            #pragma unroll
            for (int off = 32; off; off >>= 1) {
                s0 += __shfl_xor(s0, off, 64);
                s1 += __shfl_xor(s1, off, 64);
            }
            if (lane == 0) {
                sh_sc[d]     = tanhf(s0 + bmap[d]);
                sh_sc[d + 1] = tanhf(s1 + bmap[d + 1]);
            }
        }
    }
    __syncthreads();

    // scorer output + sum-of-squares partials (waves 0..7 cover 512 elems)
    if (t < DD) out2[(size_t)b * DD + t] = sh_sc[t];
    if (wave < 8) {
        float v = sh_sc[t];
        float ss = v * v;
        #pragma unroll
        for (int off = 32; off; off >>= 1) ss += __shfl_xor(ss, off, 64);
        if (lane == 0) redq[wave] = ss;
    }

    // ---- Phase B: raw scores, rows [25w, 25w+25), 12 pairs + 1 ----
    const float4 g0 = ((const float4*)sh_sc)[lane];
    const float4 g1 = ((const float4*)sh_sc)[lane + 64];
    {
        const int n0 = wave * 25;
        const float* base = embs + ((size_t)b * NN + n0) * DD;
        #pragma unroll 4
        for (int p = 0; p < 12; ++p) {
            const float4* p0 = (const float4*)(base + (size_t)(2 * p) * DD);
            const float4* p1 = (const float4*)(base + (size_t)(2 * p + 1) * DD);
            float4 a0 = p0[lane], a1 = p0[lane + 64];
            float4 c0 = p1[lane], c1 = p1[lane + 64];
            float s0 = dot8(a0, a1, g0, g1);
            float s1 = dot8(c0, c1, g0, g1);
            #pragma unroll
            for (int off = 32; off; off >>= 1) {
                s0 += __shfl_xor(s0, off, 64);
                s1 += __shfl_xor(s1, off, 64);
            }
            if (lane == 0) {
                sh_s[n0 + 2 * p]     = s0;
                sh_s[n0 + 2 * p + 1] = s1;
            }
        }
        {
            const float4* p0 = (const float4*)(base + (size_t)24 * DD);
            float4 a0 = p0[lane], a1 = p0[lane + 64];
            float s0 = dot8(a0, a1, g0, g1);
            #pragma unroll
            for (int off = 32; off; off >>= 1) s0 += __shfl_xor(s0, off, 64);
            if (lane == 0) sh_s[n0 + 24] = s0;
        }
    }
    __syncthreads();

    if (t == 0) {
        float tot = 0.f;
        #pragma unroll
        for (int i = 0; i < 8; ++i) tot += redq[i];
        mZ[0] = 1.0f / sqrtf(tot);
    }
    __syncthreads();
    const float inv = mZ[0];

    // ---- stats: block max of scaled scores ----
    const float x = (t < NN) ? sh_s[t] * inv : -FLT_MAX;
    {
        float m = x;
        #pragma unroll
        for (int off = 32; off; off >>= 1) m = fmaxf(m, __shfl_xor(m, off, 64));
        if (lane == 0) redf[wave] = m;
    }
    __syncthreads();
    if (t == 0) {
        float m = redf[0];
        #pragma unroll
        for (int i = 1; i < 16; ++i) m = fmaxf(m, redf[i]);
        mZ[1] = m;
    }
    __syncthreads();
    const float m = mZ[1];

    // ---- stats: Z and sum(exp*x) for entropy ----
    {
        float e = 0.f, wv = 0.f;
        if (t < NN) {
            float d = x - m;
            e = expf(d);
            wv = e * d;
        }
        #pragma unroll
        for (int off = 32; off; off >>= 1) {
            e  += __shfl_xor(e, off, 64);
            wv += __shfl_xor(wv, off, 64);
        }
        if (lane == 0) { redf[wave] = e; redf2[wave] = wv; }
    }
    __syncthreads();
    if (t == 0) {
        float Z = 0.f, Ws = 0.f;
        #pragma unroll
        for (int i = 0; i < 16; ++i) { Z += redf[i]; Ws += redf2[i]; }
        float logZ = logf(Z);
        mZ[2] = logZ;
        out3[b] = logZ - Ws / Z;
    }
    __syncthreads();
    const float logZ = mZ[2];

    // ---- top-K: wave 0 only, fully in-register, no barriers in the loop ----
    if (wave == 0) {
        float v0 = sh_s[lane      ] * inv;
        float v1 = sh_s[lane +  64] * inv;
        float v2 = sh_s[lane + 128] * inv;
        float v3 = sh_s[lane + 192] * inv;
        float v4 = sh_s[lane + 256] * inv;
        float v5 = sh_s[lane + 320] * inv;
        float v6 = (lane + 384 < NN) ? sh_s[lane + 384] * inv : -FLT_MAX;
        float acc = 0.f;
        for (int k = 0; k < KK; ++k) {
            float bv = v0; int bi = lane;
            if (v1 > bv) { bv = v1; bi = lane + 64; }
            if (v2 > bv) { bv = v2; bi = lane + 128; }
            if (v3 > bv) { bv = v3; bi = lane + 192; }
            if (v4 > bv) { bv = v4; bi = lane + 256; }
            if (v5 > bv) { bv = v5; bi = lane + 320; }
            if (v6 > bv) { bv = v6; bi = lane + 384; }
            #pragma unroll
            for (int off = 32; off; off >>= 1) {
                float ov = __shfl_xor(bv, off, 64);
                int   oi = __shfl_xor(bi, off, 64);
                if (ov > bv || (ov == bv && oi < bi)) { bv = ov; bi = oi; }
            }
            if (lane == 0) {
                sh_topk[k] = bi;
                sh_th[k] = tanhf(bv);
                out4[(size_t)b * KK + k] = (float)bi;
                acc += bv - m - logZ;
            }
            // clear the winner (bi is uniform across lanes after the reduce)
            v0 = (bi == lane      ) ? -FLT_MAX : v0;
            v1 = (bi == lane +  64) ? -FLT_MAX : v1;
            v2 = (bi == lane + 128) ? -FLT_MAX : v2;
            v3 = (bi == lane + 192) ? -FLT_MAX : v3;
            v4 = (bi == lane + 256) ? -FLT_MAX : v4;
            v5 = (bi == lane + 320) ? -FLT_MAX : v5;
            v6 = (bi == lane + 384) ? -FLT_MAX : v6;
        }
        if (lane == 0) out1[b] = acc / (float)KK;
    }
    __syncthreads();

    // ---- out0[b, j, k] = embs[b, topk[k], j] * th[k]; threads 0..399, k=t/20 so
    // each 20-thread group reads one contiguous 80B row-prefix ----
    if (t < NN) {
        int k = t / KK;
        int j = t - k * KK;
        float val = embs[((size_t)b * NN + sh_topk[k]) * DD + j] * sh_th[k];
        out0[(size_t)b * (KK * KK) + j * KK + k] = val;
    }
}

extern "C" void kernel_launch(void* const* d_in, const int* in_sizes, int n_in,
                              void* d_out, int out_size, void* d_ws, size_t ws_size,
                              hipStream_t stream) {
    const float* node_embs = (const float*)d_in[0];
    // d_in[1] = mask, unused
    const float* h_t   = (const float*)d_in[2];
    const float* W_map = (const float*)d_in[3];
    const float* b_map = (const float*)d_in[4];

    float* ob = (float*)d_out;
    float* out0 = ob;                       // [B,K,K] -> 102400
    float* out1 = ob + 102400;              // [B]     -> 256
    float* out2 = ob + 102656;              // [B,D]   -> 131072
    float* out3 = ob + 233728;              // [B]     -> 256
    float* out4 = ob + 233984;              // [B,K]   -> 5120

    fused_topk_kernel<<<BB, 1024, 0, stream>>>(node_embs, h_t, W_map, b_map,
                                               out0, out1, out2, out3, out4);
}